// Round 6
// baseline (214.036 us; speedup 1.0000x reference)
//
#include <hip/hip_runtime.h>
#include <cmath>

#define BB 8
#define LLEN 1024
#define CC 256
#define NH 8
#define HD 32
#define IMG 32
#define EPSBN 1e-5f
#define QSCALE 0.0625f   // 256^-0.5
#define SCLOG2E 0.09016844005556f  // QSCALE * log2(e), folded into Q

typedef short bf16x8 __attribute__((ext_vector_type(8)));
typedef short bf16x4 __attribute__((ext_vector_type(4)));
typedef float f32x4 __attribute__((ext_vector_type(4)));

static __device__ __forceinline__ unsigned short f2bf(float v) {
  union { float f; unsigned u; } a; a.f = v;
  unsigned r = a.u + 0x7fff + ((a.u >> 16) & 1);  // RNE
  return (unsigned short)(r >> 16);
}
static __device__ __forceinline__ float bf2f(unsigned short s) {
  union { unsigned u; float f; } a; a.u = ((unsigned)s) << 16; return a.f;
}

// ---------------- merged prep (R4 v1 layout -- v2 gather pack regressed) ----------------
// grid 5120: [0,4096) xy planes, [4096,4864) conv weights (fragment-major pack),
// [4864,5120) Wo hi/lo (block 4864 also zeroes the BN-stats accumulator).
__global__ __launch_bounds__(256) void k_prep(const float* __restrict__ x,
                                              const float* __restrict__ y,
                                              const float* __restrict__ w0,
                                              const float* __restrict__ w1,
                                              const float* __restrict__ w2,
                                              const float* __restrict__ Wo,
                                              short* __restrict__ xh,
                                              short* __restrict__ yh,
                                              short* __restrict__ Wp,
                                              short* __restrict__ Woh,
                                              short* __restrict__ Wol,
                                              float* __restrict__ st) {
  int bid = blockIdx.x;
  if (bid < 4096) {
    const float* s = bid >= 2048 ? y : x;
    short* d = bid >= 2048 ? yh : xh;
    size_t i = (size_t)((bid & 2047) << 8) + threadIdx.x;  // float4 index
    float4 v = ((const float4*)s)[i];
    bf16x4 o;
    o[0] = (short)f2bf(v.x); o[1] = (short)f2bf(v.y);
    o[2] = (short)f2bf(v.z); o[3] = (short)f2bf(v.w);
    *(bf16x4*)(d + i * 4) = o;
  } else if (bid < 4864) {
    int k = bid - 4096;
    int t = k >> 8, co = k & 255, ci = threadIdx.x;
    const float* w = t == 0 ? w0 : (t == 1 ? w1 : w2);
    const float* src = w + ((size_t)co * CC + ci) * 9;
    int cb = co >> 6, nt = (co >> 4) & 3, mmw = co & 15;
    int kcw = ci >> 5, quadw = (ci >> 3) & 3, e = ci & 7;
    int lanew = quadw * 16 + mmw;
    size_t base = ((size_t)(t * 4 + cb) * 8 + kcw) * 9;
#pragma unroll
    for (int tap = 0; tap < 9; ++tap)
      Wp[((base + tap) * 4 + nt) * 512 + lanew * 8 + e] = (short)f2bf(src[tap]);
  } else {
    if (bid == 4864) {
#pragma unroll
      for (int j = 0; j < 6; ++j) st[threadIdx.x * 6 + j] = 0.f;
    }
    int i = ((bid - 4864) << 8) + threadIdx.x;
    float v = Wo[i];
    unsigned short h = f2bf(v);
    Woh[i] = (short)h;
    Wol[i] = (short)f2bf(v - bf2f(h));
  }
}

// ---------------- conv3x3 MFMA v10: TLP doubling ----------------
// grid (co-tiles 4, strips 16 x 2 rows, 24=tensor*8+b) = 1536 blocks = 6/CU.
// Block: 64 co x 64 sp (2 image rows). Wave: 32 sp x 32 co (2 mt x 2 nt).
// v8/v9 intra-wave ILP tweaks were neutral/negative -- the kernel is
// LATENCY-bound at 3 waves/SIMD. v10 halves the strip to double resident
// blocks (6/CU, ~5-6 waves/SIMD): wave-level TLP is the CDNA4 mechanism
// that actually hides the ds_read/L1 chains (m114). Costs: weight vmem/CU
// x2 (3.5 MB, still under the LDS pipe), input re-read +13 MB HBM (at 11%
// BW, free). LDS 18.4 KB/block, VGPR ~90 -> occupancy not LDS/VGPR-capped.
__global__ __launch_bounds__(256, 4) void k_conv(const short* __restrict__ xh,
                                                 const short* __restrict__ yh,
                                                 const short* __restrict__ Wp,
                                                 short* __restrict__ ch,
                                                 float* __restrict__ st) {
  __shared__ __align__(16) short sI[2][136 * 32];
  __shared__ float sws[4][32];
  __shared__ float swq[4][32];

  int tid = threadIdx.x;
  int cb = blockIdx.x;
  int co0 = cb << 6;
  int r0 = blockIdx.y << 1;            // 2 image rows per strip
  int z = blockIdx.z;
  int t = z >> 3, b = z & 7;
  const short* inb = (t == 0 ? xh : yh) + (size_t)b * LLEN * CC;

  int lane = tid & 63, w = tid >> 6;
  int quad = lane >> 4, mm = lane & 15;
  int wr = w & 1, wc = w >> 1;

  int pbA[2];
#pragma unroll
  for (int mt = 0; mt < 2; ++mt) {
    int sp = wr * 32 + mt * 16 + mm;
    pbA[mt] = (sp >> 5) * 34 + (sp & 31);
  }
  const int dtap[9] = {0, 1, 2, 34, 35, 36, 68, 69, 70};

  // staging geometry (4 padded rows x 34 x 32ci = 544 b128, <=3 per thread)
  bool ivalid[3], iact[3];
  int ioff[3], sidx[3];
#pragma unroll
  for (int j = 0; j < 3; ++j) {
    int idx = tid + (j << 8);
    ivalid[j] = idx < 544;
    int sp_p = idx >> 2, cg = idx & 3;
    int pr = sp_p / 34;
    int px = sp_p - pr * 34;
    int ir = r0 - 1 + pr;
    int xx = px - 1;
    iact[j] = ivalid[j] && (ir >= 0) && (ir < IMG) && (xx >= 0) && (xx < IMG);
    ioff[j] = ((ir < 0 ? 0 : (ir > 31 ? 31 : ir)) * 32 +
               (xx < 0 ? 0 : (xx > 31 ? 31 : xx))) * CC + cg * 8;
    sidx[j] = sp_p * 32 + (((cg + (sp_p >> 1)) & 3) << 3);
  }

  const short* wlane = Wp + ((size_t)(t * 4 + cb) * 8 * 9 * 4) * 512 + lane * 8;
  // fragment offset for flat f=kc*9+tap: (f*4 + wc*2 + nt)*512

  f32x4 acc[2][2];
#pragma unroll
  for (int mt = 0; mt < 2; ++mt)
#pragma unroll
    for (int nt = 0; nt < 2; ++nt) acc[mt][nt] = (f32x4){0.f, 0.f, 0.f, 0.f};

  bf16x8 zerov = {0, 0, 0, 0, 0, 0, 0, 0};
  bf16x8 ipf[3];
#pragma unroll
  for (int j = 0; j < 3; ++j)
    ipf[j] = iact[j] ? *(const bf16x8*)(inb + ioff[j]) : zerov;

  // weight pipeline: depth 3, slots mod 4
  bf16x8 Bw[4][2];
#pragma unroll
  for (int f = 0; f < 3; ++f)
#pragma unroll
    for (int nt = 0; nt < 2; ++nt)
      Bw[f][nt] = *(const bf16x8*)(wlane + (size_t)(f * 4 + wc * 2 + nt) * 512);

  // prologue: write chunk 0 halo
#pragma unroll
  for (int j = 0; j < 3; ++j)
    if (ivalid[j]) *(bf16x8*)(sI[0] + sidx[j]) = ipf[j];
  __syncthreads();

#pragma unroll
  for (int kc = 0; kc < 8; ++kc) {
    // issue next chunk's input loads early (consumed at end of this chunk)
    if (kc < 7) {
#pragma unroll
      for (int j = 0; j < 3; ++j)
        ipf[j] = iact[j] ? *(const bf16x8*)(inb + ioff[j] + ((kc + 1) << 5)) : zerov;
    }
    const short* sc = sI[kc & 1];

#pragma unroll
    for (int tap = 0; tap < 9; ++tap) {
      const int f = kc * 9 + tap;
      // B-prefetch: depth 3
      if (f + 3 < 72) {
        const int nf = f + 3;
#pragma unroll
        for (int nt = 0; nt < 2; ++nt)
          Bw[nf & 3][nt] =
              *(const bf16x8*)(wlane + (size_t)(nf * 4 + wc * 2 + nt) * 512);
      }
      bf16x8 Af[2];
#pragma unroll
      for (int mt = 0; mt < 2; ++mt) {
        int sp_p = pbA[mt] + dtap[tap];
        Af[mt] = *(const bf16x8*)(sc + sp_p * 32 + (((quad + (sp_p >> 1)) & 3) << 3));
      }
#pragma unroll
      for (int mt = 0; mt < 2; ++mt)
#pragma unroll
        for (int nt = 0; nt < 2; ++nt)
          acc[mt][nt] = __builtin_amdgcn_mfma_f32_16x16x32_bf16(Af[mt], Bw[f & 3][nt],
                                                                acc[mt][nt], 0, 0, 0);
    }

    // write next chunk's halo into the other buffer (overlaps this chunk's taps)
    if (kc < 7) {
#pragma unroll
      for (int j = 0; j < 3; ++j)
        if (ivalid[j]) *(bf16x8*)(sI[(kc + 1) & 1] + sidx[j]) = ipf[j];
      __syncthreads();
    }
  }

  // token-major bf16 stores
  size_t tb = (size_t)t * 8192 + b * 1024 + r0 * 32;
#pragma unroll
  for (int mt = 0; mt < 2; ++mt)
#pragma unroll
    for (int nt = 0; nt < 2; ++nt)
#pragma unroll
      for (int r = 0; r < 4; ++r) {
        int sp = wr * 32 + mt * 16 + quad * 4 + r;
        ch[(tb + sp) * CC + co0 + wc * 32 + nt * 16 + mm] = (short)f2bf(acc[mt][nt][r]);
      }

  // BN stats from fp32 accumulators (wave covers 32 sp x 32 co)
  float s[2], q[2];
#pragma unroll
  for (int nt = 0; nt < 2; ++nt) {
    float ss = 0.f, qq = 0.f;
#pragma unroll
    for (int mt = 0; mt < 2; ++mt)
#pragma unroll
      for (int r = 0; r < 4; ++r) {
        float v = acc[mt][nt][r];
        ss += v;
        qq += v * v;
      }
    ss += __shfl_xor(ss, 16); ss += __shfl_xor(ss, 32);
    qq += __shfl_xor(qq, 16); qq += __shfl_xor(qq, 32);
    s[nt] = ss; q[nt] = qq;
  }
  if (quad == 0) {
#pragma unroll
    for (int nt = 0; nt < 2; ++nt) {
      sws[w][nt * 16 + mm] = s[nt];
      swq[w][nt * 16 + mm] = q[nt];
    }
  }
  __syncthreads();
  if (tid < 64) {
    int wcr = tid >> 5, cl = tid & 31;
    float S = sws[wcr * 2 + 0][cl] + sws[wcr * 2 + 1][cl];
    float Q = swq[wcr * 2 + 0][cl] + swq[wcr * 2 + 1][cl];
    atomicAdd(&st[t * 512 + co0 + tid], S);
    atomicAdd(&st[t * 512 + 256 + co0 + tid], Q);
  }
}

// ---------------- projections (fused q/k/v) with INLINE BN-fold ----------------
// Q,K written HEAD-MAJOR [(b*8+h)][1024][32] (Q pre-scaled by QSCALE*log2e);
// V written feature-major with t' interleave (t' = 16*quad+4*r+(g&3)).
__global__ __launch_bounds__(256, 2) void k_proj(const short* __restrict__ ch,
                                                 const float* __restrict__ Wq,
                                                 const float* __restrict__ Wk,
                                                 const float* __restrict__ Wv,
                                                 const float* __restrict__ gq,
                                                 const float* __restrict__ gk,
                                                 const float* __restrict__ gv,
                                                 const float* __restrict__ bq,
                                                 const float* __restrict__ bk,
                                                 const float* __restrict__ bv_,
                                                 const float* __restrict__ st,
                                                 short* __restrict__ Qh,
                                                 short* __restrict__ Kh,
                                                 short* __restrict__ Vh) {
  __shared__ __align__(16) short sT[64 * 136];   // V transpose buffer (128 t' + pad)
  __shared__ float sa[256], sdt[256];
  int tid = threadIdx.x;
  int t = blockIdx.z;
  int t0 = blockIdx.x << 7;
  int co0 = blockIdx.y << 6;
  int lane = tid & 63, w = tid >> 6;
  int quad = lane >> 4, mm = lane & 15;
  int colw = co0 + w * 16;
  const short* cht = ch + (size_t)t * 8192 * CC;

  const float* W = t == 0 ? Wq : (t == 1 ? Wk : Wv);
  const float* gamma = t == 0 ? gq : (t == 1 ? gk : gv);
  const float* beta = t == 0 ? bq : (t == 1 ? bk : bv_);

  {
    float mu = st[t * 512 + tid] * (1.f / 8192.f);
    float var = st[t * 512 + 256 + tid] * (1.f / 8192.f) - mu * mu;
    float a = gamma[tid] * rsqrtf(var + EPSBN);
    sa[tid] = a;
    sdt[tid] = beta[tid] - mu * a;
  }
  __syncthreads();

  bf16x8 Bh[8], Bl[8];
  float bacc = 0.f;
  {
    const float* wrow = W + (size_t)(colw + mm) * CC + quad * 8;
#pragma unroll
    for (int kc = 0; kc < 8; ++kc) {
      float4 w0 = *(const float4*)(wrow + kc * 32);
      float4 w1 = *(const float4*)(wrow + kc * 32 + 4);
      float wv8[8] = {w0.x, w0.y, w0.z, w0.w, w1.x, w1.y, w1.z, w1.w};
#pragma unroll
      for (int e = 0; e < 8; ++e) {
        int ci = kc * 32 + quad * 8 + e;
        float v = wv8[e] * sa[ci];
        unsigned short hh2 = f2bf(v);
        Bh[kc][e] = (short)hh2;
        Bl[kc][e] = (short)f2bf(v - bf2f(hh2));
        bacc += sdt[ci] * wv8[e];
      }
    }
  }
  bacc += __shfl_xor(bacc, 16);
  bacc += __shfl_xor(bacc, 32);
  float bv = bacc;

  int c = colw + mm;
  int hh = c >> 5, dd = c & 31;
  int bb = t0 >> 10, lbase = t0 & 1023;
  size_t hb = (size_t)(bb * 8 + hh) * 1024;

  bf16x8 A0[8], A1[8];
  auto loadA = [&](bf16x8* dst, int g) {
    const short* a = cht + (size_t)(t0 + g * 16 + mm) * CC + quad * 8;
#pragma unroll
    for (int kc = 0; kc < 8; ++kc) dst[kc] = *(const bf16x8*)(a + kc * 32);
  };
  auto compute = [&](const bf16x8* A, int g) {
    f32x4 aH = {0.f, 0.f, 0.f, 0.f}, aL = {0.f, 0.f, 0.f, 0.f};
#pragma unroll
    for (int kc = 0; kc < 8; ++kc) {
      aH = __builtin_amdgcn_mfma_f32_16x16x32_bf16(A[kc], Bh[kc], aH, 0, 0, 0);
      aL = __builtin_amdgcn_mfma_f32_16x16x32_bf16(A[kc], Bl[kc], aL, 0, 0, 0);
    }
    if (t == 0) {
#pragma unroll
      for (int r = 0; r < 4; ++r) {
        int l = lbase + g * 16 + quad * 4 + r;
        Qh[(hb + l) * 32 + dd] = (short)f2bf((aH[r] + aL[r] + bv) * SCLOG2E);
      }
    } else if (t == 1) {
#pragma unroll
      for (int r = 0; r < 4; ++r) {
        int l = lbase + g * 16 + quad * 4 + r;
        Kh[(hb + l) * 32 + dd] = (short)f2bf(aH[r] + aL[r] + bv);
      }
    } else {
#pragma unroll
      for (int r = 0; r < 4; ++r)
        sT[(w * 16 + mm) * 136 + (g >> 2) * 64 + 16 * quad + 4 * r + (g & 3)] =
            (short)f2bf(aH[r] + aL[r] + bv);
    }
  };

  loadA(A0, 0);
#pragma unroll
  for (int g = 0; g < 8; g += 2) {
    loadA(A1, g + 1);
    compute(A0, g);
    if (g + 2 < 8) loadA(A0, g + 2);
    compute(A1, g + 1);
  }

  if (t == 2) {
    __syncthreads();
    int b = t0 >> 10, l0 = t0 & 1023;
#pragma unroll
    for (int j = 0; j < 4; ++j) {
      int idx = tid + (j << 8);
      int co = idx >> 4, tg = idx & 15;
      bf16x8 v = *(const bf16x8*)(sT + co * 136 + tg * 8);
      *(bf16x8*)(Vh + ((size_t)(b * CC) + co0 + co) * LLEN + l0 + tg * 8) = v;
    }
  }
}

// ---------------- flash attention v6: single barrier per K/V tile ----------------
// grid (64 = b*8+h, 8 q-tiles), block 256: 4 waves x 32 q-rows.
__global__ __launch_bounds__(256, 2) void k_attn(const short* __restrict__ Qh,
                                                 const short* __restrict__ Kh,
                                                 const short* __restrict__ Vh,
                                                 short* __restrict__ AOh) {
  __shared__ __align__(16) short sK[2][64 * 40];   // [t][d] stride 40 (2-way free)
  __shared__ __align__(16) short sV[2][32 * 72];   // [d][t'] stride 72
  __shared__ __align__(16) short sP[4 * 32 * 72];  // per-wave [q][t'] stride 72

  int tid = threadIdx.x;
  int lane = tid & 63, w = tid >> 6;
  int quad = lane >> 4, mm = lane & 15;
  int bh = blockIdx.x;
  int b = bh >> 3, h = bh & 7;
  int l0 = blockIdx.y << 7;

  bf16x8 qf[2];
#pragma unroll
  for (int mf = 0; mf < 2; ++mf)
    qf[mf] = *(const bf16x8*)(Qh + ((size_t)bh * 1024 + l0 + w * 32 + mf * 16 + mm) * 32 +
                              quad * 8);

  f32x4 accO[2][2], accL[2];
#pragma unroll
  for (int mf = 0; mf < 2; ++mf) {
    accO[mf][0] = (f32x4){0.f, 0.f, 0.f, 0.f};
    accO[mf][1] = (f32x4){0.f, 0.f, 0.f, 0.f};
    accL[mf] = (f32x4){0.f, 0.f, 0.f, 0.f};
  }
  bf16x8 ones;
#pragma unroll
  for (int j = 0; j < 8; ++j) ones[j] = (short)0x3F80;  // bf16 1.0

  int kt = tid >> 2, kc4 = tid & 3;
  const short* kgp = Kh + ((size_t)bh * 1024 + kt) * 32 + kc4 * 8;
  int kofs = kt * 40 + kc4 * 8;
  int vd = tid >> 3, vt8 = tid & 7;
  const short* vgp = Vh + ((size_t)(b * CC) + h * HD + vd) * LLEN + vt8 * 8;
  int vofs = vd * 72 + vt8 * 8;
  short* pw = sP + w * (32 * 72);

  bf16x8 kr = *(const bf16x8*)kgp;
  bf16x8 vr = *(const bf16x8*)vgp;
  *(bf16x8*)(sK[0] + kofs) = kr;
  *(bf16x8*)(sV[0] + vofs) = vr;
  __syncthreads();

  for (int tt = 0; tt < 16; ++tt) {
    if (tt < 15) {
      kr = *(const bf16x8*)(kgp + (size_t)(tt + 1) * 64 * 32);
      vr = *(const bf16x8*)(vgp + (tt + 1) * 64);
    }
    const short* sKc = sK[tt & 1];
    const short* sVc = sV[tt & 1];

#pragma unroll
    for (int mf = 0; mf < 2; ++mf) {
      f32x4 accS[4];
#pragma unroll
      for (int nt = 0; nt < 4; ++nt) {
        bf16x8 kf = *(const bf16x8*)(sKc + (nt * 16 + mm) * 40 + quad * 8);
        f32x4 z = {0.f, 0.f, 0.f, 0.f};
        accS[nt] = __builtin_amdgcn_mfma_f32_16x16x32_bf16(qf[mf], kf, z, 0, 0, 0);
      }
#pragma unroll
      for (int r = 0; r < 4; ++r) {
        int q = mf * 16 + quad * 4 + r;
        bf16x4 pk;
#pragma unroll
        for (int nt = 0; nt < 4; ++nt) {
          union { float f; unsigned u; } cv;
          cv.f = __builtin_exp2f(accS[nt][r]);
          pk[nt] = (short)((cv.u + 0x8000u) >> 16);
        }
        *(bf16x4*)(pw + q * 72 + mm * 4) = pk;
      }
    }

#pragma unroll
    for (int kc = 0; kc < 2; ++kc) {
      bf16x8 vf0 = *(const bf16x8*)(sVc + mm * 72 + kc * 32 + quad * 8);
      bf16x8 vf1 = *(const bf16x8*)(sVc + (16 + mm) * 72 + kc * 32 + quad * 8);
#pragma unroll
      for (int mf = 0; mf < 2; ++mf) {
        bf16x8 pf = *(const bf16x8*)(pw + (mf * 16 + mm) * 72 + kc * 32 + quad * 8);
        accL[mf] = __builtin_amdgcn_mfma_f32_16x16x32_bf16(pf, ones, accL[mf], 0, 0, 0);
        accO[mf][0] = __builtin_amdgcn_mfma_f32_16x16x32_bf16(pf, vf0, accO[mf][0], 0, 0, 0);
        accO[mf][1] = __builtin_amdgcn_mfma_f32_16x16x32_bf16(pf, vf1, accO[mf][1], 0, 0, 0);
      }
    }

    if (tt < 15) {
      *(bf16x8*)(sK[(tt + 1) & 1] + kofs) = kr;
      *(bf16x8*)(sV[(tt + 1) & 1] + vofs) = vr;
      __syncthreads();
    }
  }

#pragma unroll
  for (int mf = 0; mf < 2; ++mf)
#pragma unroll
    for (int r = 0; r < 4; ++r) {
      float inv = __builtin_amdgcn_rcpf(accL[mf][r]);
      size_t token = (size_t)(b * LLEN) + l0 + w * 32 + mf * 16 + quad * 4 + r;
      AOh[token * CC + h * HD + mm] = (short)f2bf(accO[mf][0][r] * inv);
      AOh[token * CC + h * HD + 16 + mm] = (short)f2bf(accO[mf][1][r] * inv);
    }
}

// ---------------- output GEMM, register-stationary B, fp32 out ----------------
// token tile 64 (grid 512 blocks = 2/CU).
__global__ __launch_bounds__(256, 2) void k_out(const short* __restrict__ AOh,
                                                const short* __restrict__ Woh,
                                                const short* __restrict__ Wol,
                                                const float* __restrict__ bo,
                                                float* __restrict__ out) {
  int tid = threadIdx.x;
  int t0 = blockIdx.x << 6;
  int co0 = blockIdx.y << 6;
  int lane = tid & 63, w = tid >> 6;
  int quad = lane >> 4, mm = lane & 15;
  int colw = co0 + w * 16;

  bf16x8 Bh[8], Bl[8];
  {
    const short* bh = Woh + (size_t)(colw + mm) * CC + quad * 8;
    const short* bl = Wol + (size_t)(colw + mm) * CC + quad * 8;
#pragma unroll
    for (int kc = 0; kc < 8; ++kc) {
      Bh[kc] = *(const bf16x8*)(bh + kc * 32);
      Bl[kc] = *(const bf16x8*)(bl + kc * 32);
    }
  }
  float bv = bo[colw + mm];

  bf16x8 A0[8], A1[8];
  auto loadA = [&](bf16x8* dst, int g) {
    const short* a = AOh + (size_t)(t0 + g * 16 + mm) * CC + quad * 8;
#pragma unroll
    for (int kc = 0; kc < 8; ++kc) dst[kc] = *(const bf16x8*)(a + kc * 32);
  };
  auto compute = [&](const bf16x8* A, int g) {
    f32x4 aH = {0.f, 0.f, 0.f, 0.f}, aL = {0.f, 0.f, 0.f, 0.f};
#pragma unroll
    for (int kc = 0; kc < 8; ++kc) {
      aH = __builtin_amdgcn_mfma_f32_16x16x32_bf16(A[kc], Bh[kc], aH, 0, 0, 0);
      aL = __builtin_amdgcn_mfma_f32_16x16x32_bf16(A[kc], Bl[kc], aL, 0, 0, 0);
    }
#pragma unroll
    for (int r = 0; r < 4; ++r) {
      int token = t0 + g * 16 + quad * 4 + r;
      out[(size_t)token * CC + colw + mm] = aH[r] + aL[r] + bv;
    }
  };

  loadA(A0, 0);
#pragma unroll
  for (int g = 0; g < 4; g += 2) {
    loadA(A1, g + 1);
    compute(A0, g);
    if (g + 2 < 4) loadA(A0, g + 2);
    compute(A1, g + 1);
  }
}

extern "C" void kernel_launch(void* const* d_in, const int* in_sizes, int n_in,
                              void* d_out, int out_size, void* d_ws, size_t ws_size,
                              hipStream_t stream) {
  (void)in_sizes; (void)n_in; (void)out_size; (void)ws_size;
  const float* x  = (const float*)d_in[0];
  const float* y  = (const float*)d_in[1];
  const float* wq = (const float*)d_in[4];
  const float* gq = (const float*)d_in[5];
  const float* bq = (const float*)d_in[6];
  const float* wk = (const float*)d_in[7];
  const float* gk = (const float*)d_in[8];
  const float* bk = (const float*)d_in[9];
  const float* wv = (const float*)d_in[10];
  const float* gv = (const float*)d_in[11];
  const float* bv = (const float*)d_in[12];
  const float* Wq = (const float*)d_in[13];
  const float* Wk = (const float*)d_in[14];
  const float* Wv = (const float*)d_in[15];
  const float* Wo = (const float*)d_in[16];
  const float* bo = (const float*)d_in[17];
  float* out = (float*)d_out;

  const size_t NP = (size_t)8192 * 256;  // one bf16 plane = 2M shorts
  short* xh  = (short*)d_ws;
  short* yh  = xh + NP;
  short* ch  = yh + NP;            // conv-hi [3] planes
  short* Qh  = ch + 3 * NP;        // head-major [64][1024][32]
  short* Kh  = Qh + NP;            // head-major
  short* Vh  = Kh + NP;            // feature-major, t'-interleaved
  short* AOh = Vh + NP;
  short* Wp  = AOh + NP;           // packed conv weights [3][4][8][9][4][512]
  short* Woh = Wp + (size_t)3 * 9 * 65536;
  short* Wol = Woh + 65536;
  float* st  = (float*)(Wol + 65536);  // 3 x (sum256 + sumsq256)

  k_prep<<<5120, 256, 0, stream>>>(x, y, wq, wk, wv, Wo, xh, yh, Wp, Woh, Wol, st);

  k_conv<<<dim3(4, 16, 24), 256, 0, stream>>>(xh, yh, Wp, ch, st);

  k_proj<<<dim3(64, 4, 3), 256, 0, stream>>>(ch, Wq, Wk, Wv, gq, gk, gv,
                                             bq, bk, bv, st, Qh, Kh, Vh);

  k_attn<<<dim3(64, 8), 256, 0, stream>>>(Qh, Kh, Vh, AOh);

  k_out<<<dim3(128, 4), 256, 0, stream>>>(AOh, Woh, Wol, bo, out);
}

// Round 7
// 206.648 us; speedup vs baseline: 1.0358x; 1.0358x over previous
//
#include <hip/hip_runtime.h>
#include <cmath>

#define BB 8
#define LLEN 1024
#define CC 256
#define NH 8
#define HD 32
#define IMG 32
#define EPSBN 1e-5f
#define QSCALE 0.0625f   // 256^-0.5
#define SCLOG2E 0.09016844005556f  // QSCALE * log2(e), folded into Q

typedef short bf16x8 __attribute__((ext_vector_type(8)));
typedef short bf16x4 __attribute__((ext_vector_type(4)));
typedef float f32x4 __attribute__((ext_vector_type(4)));

static __device__ __forceinline__ unsigned short f2bf(float v) {
  union { float f; unsigned u; } a; a.f = v;
  unsigned r = a.u + 0x7fff + ((a.u >> 16) & 1);  // RNE
  return (unsigned short)(r >> 16);
}
static __device__ __forceinline__ float bf2f(unsigned short s) {
  union { unsigned u; float f; } a; a.u = ((unsigned)s) << 16; return a.f;
}

// ---------------- merged prep ----------------
// grid 5120: [0,4096) xy planes, [4096,4864) conv weights (fragment-major pack),
// [4864,5120) Wo hi/lo (block 4864 also zeroes the BN-stats accumulator).
__global__ __launch_bounds__(256) void k_prep(const float* __restrict__ x,
                                              const float* __restrict__ y,
                                              const float* __restrict__ w0,
                                              const float* __restrict__ w1,
                                              const float* __restrict__ w2,
                                              const float* __restrict__ Wo,
                                              short* __restrict__ xh,
                                              short* __restrict__ yh,
                                              short* __restrict__ Wp,
                                              short* __restrict__ Woh,
                                              short* __restrict__ Wol,
                                              float* __restrict__ st) {
  int bid = blockIdx.x;
  if (bid < 4096) {
    const float* s = bid >= 2048 ? y : x;
    short* d = bid >= 2048 ? yh : xh;
    size_t i = (size_t)((bid & 2047) << 8) + threadIdx.x;  // float4 index
    float4 v = ((const float4*)s)[i];
    bf16x4 o;
    o[0] = (short)f2bf(v.x); o[1] = (short)f2bf(v.y);
    o[2] = (short)f2bf(v.z); o[3] = (short)f2bf(v.w);
    *(bf16x4*)(d + i * 4) = o;
  } else if (bid < 4864) {
    int k = bid - 4096;
    int t = k >> 8, co = k & 255, ci = threadIdx.x;
    const float* w = t == 0 ? w0 : (t == 1 ? w1 : w2);
    const float* src = w + ((size_t)co * CC + ci) * 9;
    int cb = co >> 6, nt = (co >> 4) & 3, mmw = co & 15;
    int kcw = ci >> 5, quadw = (ci >> 3) & 3, e = ci & 7;
    int lanew = quadw * 16 + mmw;
    size_t base = ((size_t)(t * 4 + cb) * 8 + kcw) * 9;
#pragma unroll
    for (int tap = 0; tap < 9; ++tap)
      Wp[((base + tap) * 4 + nt) * 512 + lanew * 8 + e] = (short)f2bf(src[tap]);
  } else {
    if (bid == 4864) {
#pragma unroll
      for (int j = 0; j < 6; ++j) st[threadIdx.x * 6 + j] = 0.f;
    }
    int i = ((bid - 4864) << 8) + threadIdx.x;
    float v = Wo[i];
    unsigned short h = f2bf(v);
    Woh[i] = (short)h;
    Wol[i] = (short)f2bf(v - bf2f(h));
  }
}

// ---------------- conv3x3 MFMA v8 (best measured config) ----------------
// grid (co-tiles 4, strips 8, 24=tensor*8+b), block 256 (4 waves), 3 blocks/CU.
// Block: 64 co x 128 sp. Wave: 64 sp x 32 co (4 mt x 2 nt), 2x2 wave grid.
// sI double-buffered, one barrier per chunk; weight register pipeline depth 3.
// NOTE (rounds 3-6): v9 A-prefetch and v10 6-blocks/CU both REGRESSED;
// v8's own pipelining was neutral vs v7 -- the compiler chooses a low-register
// JIT-load schedule (VGPR=68 < live-state minimum) and re-derives scheduling.
// ~36us is this structure's compiler-structural ceiling.
__global__ __launch_bounds__(256, 3) void k_conv(const short* __restrict__ xh,
                                                 const short* __restrict__ yh,
                                                 const short* __restrict__ Wp,
                                                 short* __restrict__ ch,
                                                 float* __restrict__ st) {
  __shared__ __align__(16) short sI[2][204 * 32];
  __shared__ float sws[4][32];
  __shared__ float swq[4][32];

  int tid = threadIdx.x;
  int cb = blockIdx.x;
  int co0 = cb << 6;
  int r0 = blockIdx.y << 2;            // 4 image rows
  int z = blockIdx.z;
  int t = z >> 3, b = z & 7;
  const short* inb = (t == 0 ? xh : yh) + (size_t)b * LLEN * CC;

  int lane = tid & 63, w = tid >> 6;
  int quad = lane >> 4, mm = lane & 15;
  int wr = w & 1, wc = w >> 1;

  int pbA[4];
#pragma unroll
  for (int mt = 0; mt < 4; ++mt) {
    int sp = wr * 64 + mt * 16 + mm;
    pbA[mt] = (sp >> 5) * 34 + (sp & 31);
  }
  const int dtap[9] = {0, 1, 2, 34, 35, 36, 68, 69, 70};

  // staging geometry (4 b128 per thread, 816 total)
  bool ivalid[4], iact[4];
  int ioff[4], sidx[4];
#pragma unroll
  for (int j = 0; j < 4; ++j) {
    int idx = tid + (j << 8);
    ivalid[j] = idx < 816;
    int sp_p = idx >> 2, cg = idx & 3;
    int pr = sp_p / 34;
    int px = sp_p - pr * 34;
    int ir = r0 - 1 + pr;
    int xx = px - 1;
    iact[j] = ivalid[j] && (ir >= 0) && (ir < IMG) && (xx >= 0) && (xx < IMG);
    ioff[j] = ((ir < 0 ? 0 : ir) * 32 + (xx < 0 ? 0 : (xx > 31 ? 31 : xx))) * CC + cg * 8;
    sidx[j] = sp_p * 32 + (((cg + (sp_p >> 1)) & 3) << 3);
  }

  const short* wlane = Wp + ((size_t)(t * 4 + cb) * 8 * 9 * 4) * 512 + lane * 8;
  // fragment offset for flat f=kc*9+tap: (f*4 + wc*2 + nt)*512

  f32x4 acc[4][2];
#pragma unroll
  for (int mt = 0; mt < 4; ++mt)
#pragma unroll
    for (int nt = 0; nt < 2; ++nt) acc[mt][nt] = (f32x4){0.f, 0.f, 0.f, 0.f};

  bf16x8 zerov = {0, 0, 0, 0, 0, 0, 0, 0};
  bf16x8 ipf[4];
#pragma unroll
  for (int j = 0; j < 4; ++j)
    ipf[j] = iact[j] ? *(const bf16x8*)(inb + ioff[j]) : zerov;

  // weight pipeline: depth 3, slots mod 4
  bf16x8 Bw[4][2];
#pragma unroll
  for (int f = 0; f < 3; ++f)
#pragma unroll
    for (int nt = 0; nt < 2; ++nt)
      Bw[f][nt] = *(const bf16x8*)(wlane + (size_t)(f * 4 + wc * 2 + nt) * 512);

  // prologue: write chunk 0 halo
#pragma unroll
  for (int j = 0; j < 4; ++j)
    if (ivalid[j]) *(bf16x8*)(sI[0] + sidx[j]) = ipf[j];
  __syncthreads();

#pragma unroll
  for (int kc = 0; kc < 8; ++kc) {
    // issue next chunk's input loads early (consumed at end of this chunk)
    if (kc < 7) {
#pragma unroll
      for (int j = 0; j < 4; ++j)
        ipf[j] = iact[j] ? *(const bf16x8*)(inb + ioff[j] + ((kc + 1) << 5)) : zerov;
    }
    const short* sc = sI[kc & 1];

#pragma unroll
    for (int tap = 0; tap < 9; ++tap) {
      const int f = kc * 9 + tap;
      // B-prefetch: depth 3
      if (f + 3 < 72) {
        const int nf = f + 3;
#pragma unroll
        for (int nt = 0; nt < 2; ++nt)
          Bw[nf & 3][nt] =
              *(const bf16x8*)(wlane + (size_t)(nf * 4 + wc * 2 + nt) * 512);
      }
      bf16x8 Af[4];
#pragma unroll
      for (int mt = 0; mt < 4; ++mt) {
        int sp_p = pbA[mt] + dtap[tap];
        Af[mt] = *(const bf16x8*)(sc + sp_p * 32 + (((quad + (sp_p >> 1)) & 3) << 3));
      }
#pragma unroll
      for (int mt = 0; mt < 4; ++mt)
#pragma unroll
        for (int nt = 0; nt < 2; ++nt)
          acc[mt][nt] = __builtin_amdgcn_mfma_f32_16x16x32_bf16(Af[mt], Bw[f & 3][nt],
                                                                acc[mt][nt], 0, 0, 0);
    }

    // write next chunk's halo into the other buffer (overlaps this chunk's taps)
    if (kc < 7) {
#pragma unroll
      for (int j = 0; j < 4; ++j)
        if (ivalid[j]) *(bf16x8*)(sI[(kc + 1) & 1] + sidx[j]) = ipf[j];
      __syncthreads();
    }
  }

  // token-major bf16 stores
  size_t tb = (size_t)t * 8192 + b * 1024 + r0 * 32;
#pragma unroll
  for (int mt = 0; mt < 4; ++mt)
#pragma unroll
    for (int nt = 0; nt < 2; ++nt)
#pragma unroll
      for (int r = 0; r < 4; ++r) {
        int sp = wr * 64 + mt * 16 + quad * 4 + r;
        ch[(tb + sp) * CC + co0 + wc * 32 + nt * 16 + mm] = (short)f2bf(acc[mt][nt][r]);
      }

  // BN stats from fp32 accumulators (wave covers 64 sp x 32 co)
  float s[2], q[2];
#pragma unroll
  for (int nt = 0; nt < 2; ++nt) {
    float ss = 0.f, qq = 0.f;
#pragma unroll
    for (int mt = 0; mt < 4; ++mt)
#pragma unroll
      for (int r = 0; r < 4; ++r) {
        float v = acc[mt][nt][r];
        ss += v;
        qq += v * v;
      }
    ss += __shfl_xor(ss, 16); ss += __shfl_xor(ss, 32);
    qq += __shfl_xor(qq, 16); qq += __shfl_xor(qq, 32);
    s[nt] = ss; q[nt] = qq;
  }
  if (quad == 0) {
#pragma unroll
    for (int nt = 0; nt < 2; ++nt) {
      sws[w][nt * 16 + mm] = s[nt];
      swq[w][nt * 16 + mm] = q[nt];
    }
  }
  __syncthreads();
  if (tid < 64) {
    int wcr = tid >> 5, cl = tid & 31;
    float S = sws[wcr * 2 + 0][cl] + sws[wcr * 2 + 1][cl];
    float Q = swq[wcr * 2 + 0][cl] + swq[wcr * 2 + 1][cl];
    atomicAdd(&st[t * 512 + co0 + tid], S);
    atomicAdd(&st[t * 512 + 256 + co0 + tid], Q);
  }
}

// ---------------- projections (fused q/k/v) with INLINE BN-fold ----------------
// Q,K written HEAD-MAJOR [(b*8+h)][1024][32] (Q pre-scaled by QSCALE*log2e);
// V written feature-major with t' interleave (t' = 16*quad+4*r+(g&3)).
__global__ __launch_bounds__(256, 2) void k_proj(const short* __restrict__ ch,
                                                 const float* __restrict__ Wq,
                                                 const float* __restrict__ Wk,
                                                 const float* __restrict__ Wv,
                                                 const float* __restrict__ gq,
                                                 const float* __restrict__ gk,
                                                 const float* __restrict__ gv,
                                                 const float* __restrict__ bq,
                                                 const float* __restrict__ bk,
                                                 const float* __restrict__ bv_,
                                                 const float* __restrict__ st,
                                                 short* __restrict__ Qh,
                                                 short* __restrict__ Kh,
                                                 short* __restrict__ Vh) {
  __shared__ __align__(16) short sT[64 * 136];   // V transpose buffer (128 t' + pad)
  __shared__ float sa[256], sdt[256];
  int tid = threadIdx.x;
  int t = blockIdx.z;
  int t0 = blockIdx.x << 7;
  int co0 = blockIdx.y << 6;
  int lane = tid & 63, w = tid >> 6;
  int quad = lane >> 4, mm = lane & 15;
  int colw = co0 + w * 16;
  const short* cht = ch + (size_t)t * 8192 * CC;

  const float* W = t == 0 ? Wq : (t == 1 ? Wk : Wv);
  const float* gamma = t == 0 ? gq : (t == 1 ? gk : gv);
  const float* beta = t == 0 ? bq : (t == 1 ? bk : bv_);

  {
    float mu = st[t * 512 + tid] * (1.f / 8192.f);
    float var = st[t * 512 + 256 + tid] * (1.f / 8192.f) - mu * mu;
    float a = gamma[tid] * rsqrtf(var + EPSBN);
    sa[tid] = a;
    sdt[tid] = beta[tid] - mu * a;
  }
  __syncthreads();

  bf16x8 Bh[8], Bl[8];
  float bacc = 0.f;
  {
    const float* wrow = W + (size_t)(colw + mm) * CC + quad * 8;
#pragma unroll
    for (int kc = 0; kc < 8; ++kc) {
      float4 w0 = *(const float4*)(wrow + kc * 32);
      float4 w1 = *(const float4*)(wrow + kc * 32 + 4);
      float wv8[8] = {w0.x, w0.y, w0.z, w0.w, w1.x, w1.y, w1.z, w1.w};
#pragma unroll
      for (int e = 0; e < 8; ++e) {
        int ci = kc * 32 + quad * 8 + e;
        float v = wv8[e] * sa[ci];
        unsigned short hh2 = f2bf(v);
        Bh[kc][e] = (short)hh2;
        Bl[kc][e] = (short)f2bf(v - bf2f(hh2));
        bacc += sdt[ci] * wv8[e];
      }
    }
  }
  bacc += __shfl_xor(bacc, 16);
  bacc += __shfl_xor(bacc, 32);
  float bv = bacc;

  int c = colw + mm;
  int hh = c >> 5, dd = c & 31;
  int bb = t0 >> 10, lbase = t0 & 1023;
  size_t hb = (size_t)(bb * 8 + hh) * 1024;

  bf16x8 A0[8], A1[8];
  auto loadA = [&](bf16x8* dst, int g) {
    const short* a = cht + (size_t)(t0 + g * 16 + mm) * CC + quad * 8;
#pragma unroll
    for (int kc = 0; kc < 8; ++kc) dst[kc] = *(const bf16x8*)(a + kc * 32);
  };
  auto compute = [&](const bf16x8* A, int g) {
    f32x4 aH = {0.f, 0.f, 0.f, 0.f}, aL = {0.f, 0.f, 0.f, 0.f};
#pragma unroll
    for (int kc = 0; kc < 8; ++kc) {
      aH = __builtin_amdgcn_mfma_f32_16x16x32_bf16(A[kc], Bh[kc], aH, 0, 0, 0);
      aL = __builtin_amdgcn_mfma_f32_16x16x32_bf16(A[kc], Bl[kc], aL, 0, 0, 0);
    }
    if (t == 0) {
#pragma unroll
      for (int r = 0; r < 4; ++r) {
        int l = lbase + g * 16 + quad * 4 + r;
        Qh[(hb + l) * 32 + dd] = (short)f2bf((aH[r] + aL[r] + bv) * SCLOG2E);
      }
    } else if (t == 1) {
#pragma unroll
      for (int r = 0; r < 4; ++r) {
        int l = lbase + g * 16 + quad * 4 + r;
        Kh[(hb + l) * 32 + dd] = (short)f2bf(aH[r] + aL[r] + bv);
      }
    } else {
#pragma unroll
      for (int r = 0; r < 4; ++r)
        sT[(w * 16 + mm) * 136 + (g >> 2) * 64 + 16 * quad + 4 * r + (g & 3)] =
            (short)f2bf(aH[r] + aL[r] + bv);
    }
  };

  loadA(A0, 0);
#pragma unroll
  for (int g = 0; g < 8; g += 2) {
    loadA(A1, g + 1);
    compute(A0, g);
    if (g + 2 < 8) loadA(A0, g + 2);
    compute(A1, g + 1);
  }

  if (t == 2) {
    __syncthreads();
    int b = t0 >> 10, l0 = t0 & 1023;
#pragma unroll
    for (int j = 0; j < 4; ++j) {
      int idx = tid + (j << 8);
      int co = idx >> 4, tg = idx & 15;
      bf16x8 v = *(const bf16x8*)(sT + co * 136 + tg * 8);
      *(bf16x8*)(Vh + ((size_t)(b * CC) + co0 + co) * LLEN + l0 + tg * 8) = v;
    }
  }
}

// ---------------- flash attention v6: single barrier per K/V tile ----------------
// grid (64 = b*8+h, 8 q-tiles), block 256: 4 waves x 32 q-rows.
__global__ __launch_bounds__(256, 2) void k_attn(const short* __restrict__ Qh,
                                                 const short* __restrict__ Kh,
                                                 const short* __restrict__ Vh,
                                                 short* __restrict__ AOh) {
  __shared__ __align__(16) short sK[2][64 * 40];   // [t][d] stride 40 (2-way free)
  __shared__ __align__(16) short sV[2][32 * 72];   // [d][t'] stride 72
  __shared__ __align__(16) short sP[4 * 32 * 72];  // per-wave [q][t'] stride 72

  int tid = threadIdx.x;
  int lane = tid & 63, w = tid >> 6;
  int quad = lane >> 4, mm = lane & 15;
  int bh = blockIdx.x;
  int b = bh >> 3, h = bh & 7;
  int l0 = blockIdx.y << 7;

  bf16x8 qf[2];
#pragma unroll
  for (int mf = 0; mf < 2; ++mf)
    qf[mf] = *(const bf16x8*)(Qh + ((size_t)bh * 1024 + l0 + w * 32 + mf * 16 + mm) * 32 +
                              quad * 8);

  f32x4 accO[2][2], accL[2];
#pragma unroll
  for (int mf = 0; mf < 2; ++mf) {
    accO[mf][0] = (f32x4){0.f, 0.f, 0.f, 0.f};
    accO[mf][1] = (f32x4){0.f, 0.f, 0.f, 0.f};
    accL[mf] = (f32x4){0.f, 0.f, 0.f, 0.f};
  }
  bf16x8 ones;
#pragma unroll
  for (int j = 0; j < 8; ++j) ones[j] = (short)0x3F80;  // bf16 1.0

  int kt = tid >> 2, kc4 = tid & 3;
  const short* kgp = Kh + ((size_t)bh * 1024 + kt) * 32 + kc4 * 8;
  int kofs = kt * 40 + kc4 * 8;
  int vd = tid >> 3, vt8 = tid & 7;
  const short* vgp = Vh + ((size_t)(b * CC) + h * HD + vd) * LLEN + vt8 * 8;
  int vofs = vd * 72 + vt8 * 8;
  short* pw = sP + w * (32 * 72);

  bf16x8 kr = *(const bf16x8*)kgp;
  bf16x8 vr = *(const bf16x8*)vgp;
  *(bf16x8*)(sK[0] + kofs) = kr;
  *(bf16x8*)(sV[0] + vofs) = vr;
  __syncthreads();

  for (int tt = 0; tt < 16; ++tt) {
    if (tt < 15) {
      kr = *(const bf16x8*)(kgp + (size_t)(tt + 1) * 64 * 32);
      vr = *(const bf16x8*)(vgp + (tt + 1) * 64);
    }
    const short* sKc = sK[tt & 1];
    const short* sVc = sV[tt & 1];

#pragma unroll
    for (int mf = 0; mf < 2; ++mf) {
      f32x4 accS[4];
#pragma unroll
      for (int nt = 0; nt < 4; ++nt) {
        bf16x8 kf = *(const bf16x8*)(sKc + (nt * 16 + mm) * 40 + quad * 8);
        f32x4 z = {0.f, 0.f, 0.f, 0.f};
        accS[nt] = __builtin_amdgcn_mfma_f32_16x16x32_bf16(qf[mf], kf, z, 0, 0, 0);
      }
#pragma unroll
      for (int r = 0; r < 4; ++r) {
        int q = mf * 16 + quad * 4 + r;
        bf16x4 pk;
#pragma unroll
        for (int nt = 0; nt < 4; ++nt) {
          union { float f; unsigned u; } cv;
          cv.f = __builtin_exp2f(accS[nt][r]);
          pk[nt] = (short)((cv.u + 0x8000u) >> 16);
        }
        *(bf16x4*)(pw + q * 72 + mm * 4) = pk;
      }
    }

#pragma unroll
    for (int kc = 0; kc < 2; ++kc) {
      bf16x8 vf0 = *(const bf16x8*)(sVc + mm * 72 + kc * 32 + quad * 8);
      bf16x8 vf1 = *(const bf16x8*)(sVc + (16 + mm) * 72 + kc * 32 + quad * 8);
#pragma unroll
      for (int mf = 0; mf < 2; ++mf) {
        bf16x8 pf = *(const bf16x8*)(pw + (mf * 16 + mm) * 72 + kc * 32 + quad * 8);
        accL[mf] = __builtin_amdgcn_mfma_f32_16x16x32_bf16(pf, ones, accL[mf], 0, 0, 0);
        accO[mf][0] = __builtin_amdgcn_mfma_f32_16x16x32_bf16(pf, vf0, accO[mf][0], 0, 0, 0);
        accO[mf][1] = __builtin_amdgcn_mfma_f32_16x16x32_bf16(pf, vf1, accO[mf][1], 0, 0, 0);
      }
    }

    if (tt < 15) {
      *(bf16x8*)(sK[(tt + 1) & 1] + kofs) = kr;
      *(bf16x8*)(sV[(tt + 1) & 1] + vofs) = vr;
      __syncthreads();
    }
  }

#pragma unroll
  for (int mf = 0; mf < 2; ++mf)
#pragma unroll
    for (int r = 0; r < 4; ++r) {
      float inv = __builtin_amdgcn_rcpf(accL[mf][r]);
      size_t token = (size_t)(b * LLEN) + l0 + w * 32 + mf * 16 + quad * 4 + r;
      AOh[token * CC + h * HD + mm] = (short)f2bf(accO[mf][0][r] * inv);
      AOh[token * CC + h * HD + 16 + mm] = (short)f2bf(accO[mf][1][r] * inv);
    }
}

// ---------------- output GEMM, register-stationary B, fp32 out ----------------
// token tile 64 (grid 512 blocks = 2/CU).
__global__ __launch_bounds__(256, 2) void k_out(const short* __restrict__ AOh,
                                                const short* __restrict__ Woh,
                                                const short* __restrict__ Wol,
                                                const float* __restrict__ bo,
                                                float* __restrict__ out) {
  int tid = threadIdx.x;
  int t0 = blockIdx.x << 6;
  int co0 = blockIdx.y << 6;
  int lane = tid & 63, w = tid >> 6;
  int quad = lane >> 4, mm = lane & 15;
  int colw = co0 + w * 16;

  bf16x8 Bh[8], Bl[8];
  {
    const short* bh = Woh + (size_t)(colw + mm) * CC + quad * 8;
    const short* bl = Wol + (size_t)(colw + mm) * CC + quad * 8;
#pragma unroll
    for (int kc = 0; kc < 8; ++kc) {
      Bh[kc] = *(const bf16x8*)(bh + kc * 32);
      Bl[kc] = *(const bf16x8*)(bl + kc * 32);
    }
  }
  float bv = bo[colw + mm];

  bf16x8 A0[8], A1[8];
  auto loadA = [&](bf16x8* dst, int g) {
    const short* a = AOh + (size_t)(t0 + g * 16 + mm) * CC + quad * 8;
#pragma unroll
    for (int kc = 0; kc < 8; ++kc) dst[kc] = *(const bf16x8*)(a + kc * 32);
  };
  auto compute = [&](const bf16x8* A, int g) {
    f32x4 aH = {0.f, 0.f, 0.f, 0.f}, aL = {0.f, 0.f, 0.f, 0.f};
#pragma unroll
    for (int kc = 0; kc < 8; ++kc) {
      aH = __builtin_amdgcn_mfma_f32_16x16x32_bf16(A[kc], Bh[kc], aH, 0, 0, 0);
      aL = __builtin_amdgcn_mfma_f32_16x16x32_bf16(A[kc], Bl[kc], aL, 0, 0, 0);
    }
#pragma unroll
    for (int r = 0; r < 4; ++r) {
      int token = t0 + g * 16 + quad * 4 + r;
      out[(size_t)token * CC + colw + mm] = aH[r] + aL[r] + bv;
    }
  };

  loadA(A0, 0);
#pragma unroll
  for (int g = 0; g < 4; g += 2) {
    loadA(A1, g + 1);
    compute(A0, g);
    if (g + 2 < 4) loadA(A0, g + 2);
    compute(A1, g + 1);
  }
}

extern "C" void kernel_launch(void* const* d_in, const int* in_sizes, int n_in,
                              void* d_out, int out_size, void* d_ws, size_t ws_size,
                              hipStream_t stream) {
  (void)in_sizes; (void)n_in; (void)out_size; (void)ws_size;
  const float* x  = (const float*)d_in[0];
  const float* y  = (const float*)d_in[1];
  const float* wq = (const float*)d_in[4];
  const float* gq = (const float*)d_in[5];
  const float* bq = (const float*)d_in[6];
  const float* wk = (const float*)d_in[7];
  const float* gk = (const float*)d_in[8];
  const float* bk = (const float*)d_in[9];
  const float* wv = (const float*)d_in[10];
  const float* gv = (const float*)d_in[11];
  const float* bv = (const float*)d_in[12];
  const float* Wq = (const float*)d_in[13];
  const float* Wk = (const float*)d_in[14];
  const float* Wv = (const float*)d_in[15];
  const float* Wo = (const float*)d_in[16];
  const float* bo = (const float*)d_in[17];
  float* out = (float*)d_out;

  const size_t NP = (size_t)8192 * 256;  // one bf16 plane = 2M shorts
  short* xh  = (short*)d_ws;
  short* yh  = xh + NP;
  short* ch  = yh + NP;            // conv-hi [3] planes
  short* Qh  = ch + 3 * NP;        // head-major [64][1024][32]
  short* Kh  = Qh + NP;            // head-major
  short* Vh  = Kh + NP;            // feature-major, t'-interleaved
  short* AOh = Vh + NP;
  short* Wp  = AOh + NP;           // packed conv weights [3][4][8][9][4][512]
  short* Woh = Wp + (size_t)3 * 9 * 65536;
  short* Wol = Woh + 65536;
  float* st  = (float*)(Wol + 65536);  // 3 x (sum256 + sumsq256)

  k_prep<<<5120, 256, 0, stream>>>(x, y, wq, wk, wv, Wo, xh, yh, Wp, Woh, Wol, st);

  k_conv<<<dim3(4, 8, 24), 256, 0, stream>>>(xh, yh, Wp, ch, st);

  k_proj<<<dim3(64, 4, 3), 256, 0, stream>>>(ch, Wq, Wk, Wv, gq, gk, gv,
                                             bq, bk, bv, st, Qh, Kh, Vh);

  k_attn<<<dim3(64, 8), 256, 0, stream>>>(Qh, Kh, Vh, AOh);

  k_out<<<dim3(128, 4), 256, 0, stream>>>(AOh, Woh, Wol, bo, out);
}

// Round 8
// 205.184 us; speedup vs baseline: 1.0431x; 1.0071x over previous
//
#include <hip/hip_runtime.h>
#include <cmath>

#define BB 8
#define LLEN 1024
#define CC 256
#define NH 8
#define HD 32
#define IMG 32
#define EPSBN 1e-5f
#define QSCALE 0.0625f   // 256^-0.5
#define SCLOG2E 0.09016844005556f  // QSCALE * log2(e), folded into Q

typedef short bf16x8 __attribute__((ext_vector_type(8)));
typedef short bf16x4 __attribute__((ext_vector_type(4)));
typedef float f32x4 __attribute__((ext_vector_type(4)));

static __device__ __forceinline__ unsigned short f2bf(float v) {
  union { float f; unsigned u; } a; a.f = v;
  unsigned r = a.u + 0x7fff + ((a.u >> 16) & 1);  // RNE
  return (unsigned short)(r >> 16);
}
static __device__ __forceinline__ float bf2f(unsigned short s) {
  union { unsigned u; float f; } a; a.u = ((unsigned)s) << 16; return a.f;
}

// async global->LDS 16B DMA (per-lane global src, wave-uniform LDS base + lane*16)
static __device__ __forceinline__ void gll16(const void* g, void* l) {
  __builtin_amdgcn_global_load_lds(
      (const __attribute__((address_space(1))) unsigned int*)g,
      (__attribute__((address_space(3))) unsigned int*)l, 16, 0, 0);
}

// ---------------- merged prep ----------------
// grid 5120: [0,4096) xy planes, [4096,4864) conv weights (fragment-major pack),
// [4864,5120) Wo hi/lo (block 4864 also zeroes BN-stats accumulator + zpad).
__global__ __launch_bounds__(256) void k_prep(const float* __restrict__ x,
                                              const float* __restrict__ y,
                                              const float* __restrict__ w0,
                                              const float* __restrict__ w1,
                                              const float* __restrict__ w2,
                                              const float* __restrict__ Wo,
                                              short* __restrict__ xh,
                                              short* __restrict__ yh,
                                              short* __restrict__ Wp,
                                              short* __restrict__ Woh,
                                              short* __restrict__ Wol,
                                              float* __restrict__ st,
                                              float* __restrict__ zf) {
  int bid = blockIdx.x;
  if (bid < 4096) {
    const float* s = bid >= 2048 ? y : x;
    short* d = bid >= 2048 ? yh : xh;
    size_t i = (size_t)((bid & 2047) << 8) + threadIdx.x;  // float4 index
    float4 v = ((const float4*)s)[i];
    bf16x4 o;
    o[0] = (short)f2bf(v.x); o[1] = (short)f2bf(v.y);
    o[2] = (short)f2bf(v.z); o[3] = (short)f2bf(v.w);
    *(bf16x4*)(d + i * 4) = o;
  } else if (bid < 4864) {
    int k = bid - 4096;
    int t = k >> 8, co = k & 255, ci = threadIdx.x;
    const float* w = t == 0 ? w0 : (t == 1 ? w1 : w2);
    const float* src = w + ((size_t)co * CC + ci) * 9;
    int cb = co >> 6, nt = (co >> 4) & 3, mmw = co & 15;
    int kcw = ci >> 5, quadw = (ci >> 3) & 3, e = ci & 7;
    int lanew = quadw * 16 + mmw;
    size_t base = ((size_t)(t * 4 + cb) * 8 + kcw) * 9;
#pragma unroll
    for (int tap = 0; tap < 9; ++tap)
      Wp[((base + tap) * 4 + nt) * 512 + lanew * 8 + e] = (short)f2bf(src[tap]);
  } else {
    if (bid == 4864) {
#pragma unroll
      for (int j = 0; j < 6; ++j) st[threadIdx.x * 6 + j] = 0.f;
      zf[threadIdx.x] = 0.f;
      zf[256 + threadIdx.x] = 0.f;
    }
    int i = ((bid - 4864) << 8) + threadIdx.x;
    float v = Wo[i];
    unsigned short h = f2bf(v);
    Woh[i] = (short)h;
    Wol[i] = (short)f2bf(v - bf2f(h));
  }
}

// ---------------- conv3x3 MFMA v11: global_load_lds staging ----------------
// grid (co-tiles 4, strips 8, 24=tensor*8+b), block 256 (4 waves), 3 blocks/CU.
// Block: 64 co x 128 sp. Wave: 64 sp x 32 co (4 mt x 2 nt), 2x2 wave grid.
// v11: input staging via __builtin_amdgcn_global_load_lds (16B DMA, no VGPR
// round-trip, no ds_write). LDS dest is LINEAR (rule 21); the read-swizzle is
// achieved by PRE-SWIZZLING the per-lane global source: physical slot p=tid&3
// holds group cg=(p-(sp_p>>1))&3. OOB halo lanes DMA from a zeroed global
// scratch (zpad). Staging for chunk kc+1 is issued at the TOP of chunk kc --
// it flies during the 9 taps; the end-of-chunk __syncthreads (vmcnt0+barrier)
// drains it. This is the m97 async mechanism, impossible with reg staging.
__global__ __launch_bounds__(256, 3) void k_conv(const short* __restrict__ xh,
                                                 const short* __restrict__ yh,
                                                 const short* __restrict__ Wp,
                                                 const short* __restrict__ zpad,
                                                 short* __restrict__ ch,
                                                 float* __restrict__ st) {
  __shared__ __align__(16) short sI[2][208 * 32];   // 832 slots (816 real + pad)
  __shared__ float sws[4][32];
  __shared__ float swq[4][32];

  int tid = threadIdx.x;
  int cb = blockIdx.x;
  int co0 = cb << 6;
  int r0 = blockIdx.y << 2;            // 4 image rows
  int z = blockIdx.z;
  int t = z >> 3, b = z & 7;
  const short* inb = (t == 0 ? xh : yh) + (size_t)b * LLEN * CC;

  int lane = tid & 63, w = tid >> 6;
  int quad = lane >> 4, mm = lane & 15;
  int wr = w & 1, wc = w >> 1;

  int pbA[4];
#pragma unroll
  for (int mt = 0; mt < 4; ++mt) {
    int sp = wr * 64 + mt * 16 + mm;
    pbA[mt] = (sp >> 5) * 34 + (sp & 31);
  }
  const int dtap[9] = {0, 1, 2, 34, 35, 36, 68, 69, 70};

  // staging geometry: slot = tid + j*256; linear LDS dest, pre-swizzled source.
  const short* gsrc[4];
#pragma unroll
  for (int j = 0; j < 4; ++j) {
    int slot = tid + (j << 8);
    int sp_p = slot >> 2;
    int pr = sp_p / 34;
    int px = sp_p - pr * 34;
    int ir = r0 - 1 + pr;
    int xx = px - 1;
    bool act = (slot < 816) && (ir >= 0) && (ir < IMG) && (xx >= 0) && (xx < IMG);
    int cg = ((tid & 3) - (slot >> 3)) & 3;   // inverse swizzle on the source
    gsrc[j] = act ? inb + ((ir < 0 ? 0 : ir) * 32 + (xx < 0 ? 0 : (xx > 31 ? 31 : xx)))
                        * CC + cg * 8
                  : zpad + (tid & 63) * 8;
  }

  const short* wlane = Wp + ((size_t)(t * 4 + cb) * 8 * 9 * 4) * 512 + lane * 8;
  // fragment offset for flat f=kc*9+tap: (f*4 + wc*2 + nt)*512

  f32x4 acc[4][2];
#pragma unroll
  for (int mt = 0; mt < 4; ++mt)
#pragma unroll
    for (int nt = 0; nt < 2; ++nt) acc[mt][nt] = (f32x4){0.f, 0.f, 0.f, 0.f};

  // weight pipeline: depth 3, slots mod 4
  bf16x8 Bw[4][2];
#pragma unroll
  for (int f = 0; f < 3; ++f)
#pragma unroll
    for (int nt = 0; nt < 2; ++nt)
      Bw[f][nt] = *(const bf16x8*)(wlane + (size_t)(f * 4 + wc * 2 + nt) * 512);

  // issue staging for buffer `buf` with channel offset ci0 (13 wave-calls: 4/3/3/3)
  auto stage = [&](int buf, int ci0) {
#pragma unroll
    for (int j = 0; j < 4; ++j) {
      if (j < 3 || w == 0) {
        short* dst = sI[buf] + j * 2048 + w * 512;   // wave-uniform base
        gll16(gsrc[j] + ci0, dst);
      }
    }
  };

  // prologue: chunk 0
  stage(0, 0);
  __syncthreads();

#pragma unroll
  for (int kc = 0; kc < 8; ++kc) {
    // issue chunk kc+1's DMA into the other buffer; it flies under the taps
    if (kc < 7) stage((kc + 1) & 1, (kc + 1) << 5);
    const short* sc = sI[kc & 1];

#pragma unroll
    for (int tap = 0; tap < 9; ++tap) {
      const int f = kc * 9 + tap;
      // B-prefetch: depth 3
      if (f + 3 < 72) {
        const int nf = f + 3;
#pragma unroll
        for (int nt = 0; nt < 2; ++nt)
          Bw[nf & 3][nt] =
              *(const bf16x8*)(wlane + (size_t)(nf * 4 + wc * 2 + nt) * 512);
      }
      bf16x8 Af[4];
#pragma unroll
      for (int mt = 0; mt < 4; ++mt) {
        int sp_p = pbA[mt] + dtap[tap];
        Af[mt] = *(const bf16x8*)(sc + sp_p * 32 + (((quad + (sp_p >> 1)) & 3) << 3));
      }
#pragma unroll
      for (int mt = 0; mt < 4; ++mt)
#pragma unroll
        for (int nt = 0; nt < 2; ++nt)
          acc[mt][nt] = __builtin_amdgcn_mfma_f32_16x16x32_bf16(Af[mt], Bw[f & 3][nt],
                                                                acc[mt][nt], 0, 0, 0);
    }

    // drain this chunk's prefetch DMA (vmcnt0) + sync before consuming it
    if (kc < 7) __syncthreads();
  }

  // token-major bf16 stores
  size_t tb = (size_t)t * 8192 + b * 1024 + r0 * 32;
#pragma unroll
  for (int mt = 0; mt < 4; ++mt)
#pragma unroll
    for (int nt = 0; nt < 2; ++nt)
#pragma unroll
      for (int r = 0; r < 4; ++r) {
        int sp = wr * 64 + mt * 16 + quad * 4 + r;
        ch[(tb + sp) * CC + co0 + wc * 32 + nt * 16 + mm] = (short)f2bf(acc[mt][nt][r]);
      }

  // BN stats from fp32 accumulators (wave covers 64 sp x 32 co)
  float s[2], q[2];
#pragma unroll
  for (int nt = 0; nt < 2; ++nt) {
    float ss = 0.f, qq = 0.f;
#pragma unroll
    for (int mt = 0; mt < 4; ++mt)
#pragma unroll
      for (int r = 0; r < 4; ++r) {
        float v = acc[mt][nt][r];
        ss += v;
        qq += v * v;
      }
    ss += __shfl_xor(ss, 16); ss += __shfl_xor(ss, 32);
    qq += __shfl_xor(qq, 16); qq += __shfl_xor(qq, 32);
    s[nt] = ss; q[nt] = qq;
  }
  if (quad == 0) {
#pragma unroll
    for (int nt = 0; nt < 2; ++nt) {
      sws[w][nt * 16 + mm] = s[nt];
      swq[w][nt * 16 + mm] = q[nt];
    }
  }
  __syncthreads();
  if (tid < 64) {
    int wcr = tid >> 5, cl = tid & 31;
    float S = sws[wcr * 2 + 0][cl] + sws[wcr * 2 + 1][cl];
    float Q = swq[wcr * 2 + 0][cl] + swq[wcr * 2 + 1][cl];
    atomicAdd(&st[t * 512 + co0 + tid], S);
    atomicAdd(&st[t * 512 + 256 + co0 + tid], Q);
  }
}

// ---------------- projections (fused q/k/v) with INLINE BN-fold ----------------
// Q,K written HEAD-MAJOR [(b*8+h)][1024][32] (Q pre-scaled by QSCALE*log2e);
// V written feature-major with t' interleave (t' = 16*quad+4*r+(g&3)).
__global__ __launch_bounds__(256, 2) void k_proj(const short* __restrict__ ch,
                                                 const float* __restrict__ Wq,
                                                 const float* __restrict__ Wk,
                                                 const float* __restrict__ Wv,
                                                 const float* __restrict__ gq,
                                                 const float* __restrict__ gk,
                                                 const float* __restrict__ gv,
                                                 const float* __restrict__ bq,
                                                 const float* __restrict__ bk,
                                                 const float* __restrict__ bv_,
                                                 const float* __restrict__ st,
                                                 short* __restrict__ Qh,
                                                 short* __restrict__ Kh,
                                                 short* __restrict__ Vh) {
  __shared__ __align__(16) short sT[64 * 136];   // V transpose buffer (128 t' + pad)
  __shared__ float sa[256], sdt[256];
  int tid = threadIdx.x;
  int t = blockIdx.z;
  int t0 = blockIdx.x << 7;
  int co0 = blockIdx.y << 6;
  int lane = tid & 63, w = tid >> 6;
  int quad = lane >> 4, mm = lane & 15;
  int colw = co0 + w * 16;
  const short* cht = ch + (size_t)t * 8192 * CC;

  const float* W = t == 0 ? Wq : (t == 1 ? Wk : Wv);
  const float* gamma = t == 0 ? gq : (t == 1 ? gk : gv);
  const float* beta = t == 0 ? bq : (t == 1 ? bk : bv_);

  {
    float mu = st[t * 512 + tid] * (1.f / 8192.f);
    float var = st[t * 512 + 256 + tid] * (1.f / 8192.f) - mu * mu;
    float a = gamma[tid] * rsqrtf(var + EPSBN);
    sa[tid] = a;
    sdt[tid] = beta[tid] - mu * a;
  }
  __syncthreads();

  bf16x8 Bh[8], Bl[8];
  float bacc = 0.f;
  {
    const float* wrow = W + (size_t)(colw + mm) * CC + quad * 8;
#pragma unroll
    for (int kc = 0; kc < 8; ++kc) {
      float4 w0 = *(const float4*)(wrow + kc * 32);
      float4 w1 = *(const float4*)(wrow + kc * 32 + 4);
      float wv8[8] = {w0.x, w0.y, w0.z, w0.w, w1.x, w1.y, w1.z, w1.w};
#pragma unroll
      for (int e = 0; e < 8; ++e) {
        int ci = kc * 32 + quad * 8 + e;
        float v = wv8[e] * sa[ci];
        unsigned short hh2 = f2bf(v);
        Bh[kc][e] = (short)hh2;
        Bl[kc][e] = (short)f2bf(v - bf2f(hh2));
        bacc += sdt[ci] * wv8[e];
      }
    }
  }
  bacc += __shfl_xor(bacc, 16);
  bacc += __shfl_xor(bacc, 32);
  float bv = bacc;

  int c = colw + mm;
  int hh = c >> 5, dd = c & 31;
  int bb = t0 >> 10, lbase = t0 & 1023;
  size_t hb = (size_t)(bb * 8 + hh) * 1024;

  bf16x8 A0[8], A1[8];
  auto loadA = [&](bf16x8* dst, int g) {
    const short* a = cht + (size_t)(t0 + g * 16 + mm) * CC + quad * 8;
#pragma unroll
    for (int kc = 0; kc < 8; ++kc) dst[kc] = *(const bf16x8*)(a + kc * 32);
  };
  auto compute = [&](const bf16x8* A, int g) {
    f32x4 aH = {0.f, 0.f, 0.f, 0.f}, aL = {0.f, 0.f, 0.f, 0.f};
#pragma unroll
    for (int kc = 0; kc < 8; ++kc) {
      aH = __builtin_amdgcn_mfma_f32_16x16x32_bf16(A[kc], Bh[kc], aH, 0, 0, 0);
      aL = __builtin_amdgcn_mfma_f32_16x16x32_bf16(A[kc], Bl[kc], aL, 0, 0, 0);
    }
    if (t == 0) {
#pragma unroll
      for (int r = 0; r < 4; ++r) {
        int l = lbase + g * 16 + quad * 4 + r;
        Qh[(hb + l) * 32 + dd] = (short)f2bf((aH[r] + aL[r] + bv) * SCLOG2E);
      }
    } else if (t == 1) {
#pragma unroll
      for (int r = 0; r < 4; ++r) {
        int l = lbase + g * 16 + quad * 4 + r;
        Kh[(hb + l) * 32 + dd] = (short)f2bf(aH[r] + aL[r] + bv);
      }
    } else {
#pragma unroll
      for (int r = 0; r < 4; ++r)
        sT[(w * 16 + mm) * 136 + (g >> 2) * 64 + 16 * quad + 4 * r + (g & 3)] =
            (short)f2bf(aH[r] + aL[r] + bv);
    }
  };

  loadA(A0, 0);
#pragma unroll
  for (int g = 0; g < 8; g += 2) {
    loadA(A1, g + 1);
    compute(A0, g);
    if (g + 2 < 8) loadA(A0, g + 2);
    compute(A1, g + 1);
  }

  if (t == 2) {
    __syncthreads();
    int b = t0 >> 10, l0 = t0 & 1023;
#pragma unroll
    for (int j = 0; j < 4; ++j) {
      int idx = tid + (j << 8);
      int co = idx >> 4, tg = idx & 15;
      bf16x8 v = *(const bf16x8*)(sT + co * 136 + tg * 8);
      *(bf16x8*)(Vh + ((size_t)(b * CC) + co0 + co) * LLEN + l0 + tg * 8) = v;
    }
  }
}

// ---------------- flash attention v6: single barrier per K/V tile ----------------
// grid (64 = b*8+h, 8 q-tiles), block 256: 4 waves x 32 q-rows.
__global__ __launch_bounds__(256, 2) void k_attn(const short* __restrict__ Qh,
                                                 const short* __restrict__ Kh,
                                                 const short* __restrict__ Vh,
                                                 short* __restrict__ AOh) {
  __shared__ __align__(16) short sK[2][64 * 40];   // [t][d] stride 40 (2-way free)
  __shared__ __align__(16) short sV[2][32 * 72];   // [d][t'] stride 72
  __shared__ __align__(16) short sP[4 * 32 * 72];  // per-wave [q][t'] stride 72

  int tid = threadIdx.x;
  int lane = tid & 63, w = tid >> 6;
  int quad = lane >> 4, mm = lane & 15;
  int bh = blockIdx.x;
  int b = bh >> 3, h = bh & 7;
  int l0 = blockIdx.y << 7;

  bf16x8 qf[2];
#pragma unroll
  for (int mf = 0; mf < 2; ++mf)
    qf[mf] = *(const bf16x8*)(Qh + ((size_t)bh * 1024 + l0 + w * 32 + mf * 16 + mm) * 32 +
                              quad * 8);

  f32x4 accO[2][2], accL[2];
#pragma unroll
  for (int mf = 0; mf < 2; ++mf) {
    accO[mf][0] = (f32x4){0.f, 0.f, 0.f, 0.f};
    accO[mf][1] = (f32x4){0.f, 0.f, 0.f, 0.f};
    accL[mf] = (f32x4){0.f, 0.f, 0.f, 0.f};
  }
  bf16x8 ones;
#pragma unroll
  for (int j = 0; j < 8; ++j) ones[j] = (short)0x3F80;  // bf16 1.0

  int kt = tid >> 2, kc4 = tid & 3;
  const short* kgp = Kh + ((size_t)bh * 1024 + kt) * 32 + kc4 * 8;
  int kofs = kt * 40 + kc4 * 8;
  int vd = tid >> 3, vt8 = tid & 7;
  const short* vgp = Vh + ((size_t)(b * CC) + h * HD + vd) * LLEN + vt8 * 8;
  int vofs = vd * 72 + vt8 * 8;
  short* pw = sP + w * (32 * 72);

  bf16x8 kr = *(const bf16x8*)kgp;
  bf16x8 vr = *(const bf16x8*)vgp;
  *(bf16x8*)(sK[0] + kofs) = kr;
  *(bf16x8*)(sV[0] + vofs) = vr;
  __syncthreads();

  for (int tt = 0; tt < 16; ++tt) {
    if (tt < 15) {
      kr = *(const bf16x8*)(kgp + (size_t)(tt + 1) * 64 * 32);
      vr = *(const bf16x8*)(vgp + (tt + 1) * 64);
    }
    const short* sKc = sK[tt & 1];
    const short* sVc = sV[tt & 1];

#pragma unroll
    for (int mf = 0; mf < 2; ++mf) {
      f32x4 accS[4];
#pragma unroll
      for (int nt = 0; nt < 4; ++nt) {
        bf16x8 kf = *(const bf16x8*)(sKc + (nt * 16 + mm) * 40 + quad * 8);
        f32x4 z = {0.f, 0.f, 0.f, 0.f};
        accS[nt] = __builtin_amdgcn_mfma_f32_16x16x32_bf16(qf[mf], kf, z, 0, 0, 0);
      }
#pragma unroll
      for (int r = 0; r < 4; ++r) {
        int q = mf * 16 + quad * 4 + r;
        bf16x4 pk;
#pragma unroll
        for (int nt = 0; nt < 4; ++nt) {
          union { float f; unsigned u; } cv;
          cv.f = __builtin_exp2f(accS[nt][r]);
          pk[nt] = (short)((cv.u + 0x8000u) >> 16);
        }
        *(bf16x4*)(pw + q * 72 + mm * 4) = pk;
      }
    }

#pragma unroll
    for (int kc = 0; kc < 2; ++kc) {
      bf16x8 vf0 = *(const bf16x8*)(sVc + mm * 72 + kc * 32 + quad * 8);
      bf16x8 vf1 = *(const bf16x8*)(sVc + (16 + mm) * 72 + kc * 32 + quad * 8);
#pragma unroll
      for (int mf = 0; mf < 2; ++mf) {
        bf16x8 pf = *(const bf16x8*)(pw + (mf * 16 + mm) * 72 + kc * 32 + quad * 8);
        accL[mf] = __builtin_amdgcn_mfma_f32_16x16x32_bf16(pf, ones, accL[mf], 0, 0, 0);
        accO[mf][0] = __builtin_amdgcn_mfma_f32_16x16x32_bf16(pf, vf0, accO[mf][0], 0, 0, 0);
        accO[mf][1] = __builtin_amdgcn_mfma_f32_16x16x32_bf16(pf, vf1, accO[mf][1], 0, 0, 0);
      }
    }

    if (tt < 15) {
      *(bf16x8*)(sK[(tt + 1) & 1] + kofs) = kr;
      *(bf16x8*)(sV[(tt + 1) & 1] + vofs) = vr;
      __syncthreads();
    }
  }

#pragma unroll
  for (int mf = 0; mf < 2; ++mf)
#pragma unroll
    for (int r = 0; r < 4; ++r) {
      float inv = __builtin_amdgcn_rcpf(accL[mf][r]);
      size_t token = (size_t)(b * LLEN) + l0 + w * 32 + mf * 16 + quad * 4 + r;
      AOh[token * CC + h * HD + mm] = (short)f2bf(accO[mf][0][r] * inv);
      AOh[token * CC + h * HD + 16 + mm] = (short)f2bf(accO[mf][1][r] * inv);
    }
}

// ---------------- output GEMM, register-stationary B, fp32 out ----------------
// token tile 64 (grid 512 blocks = 2/CU).
__global__ __launch_bounds__(256, 2) void k_out(const short* __restrict__ AOh,
                                                const short* __restrict__ Woh,
                                                const short* __restrict__ Wol,
                                                const float* __restrict__ bo,
                                                float* __restrict__ out) {
  int tid = threadIdx.x;
  int t0 = blockIdx.x << 6;
  int co0 = blockIdx.y << 6;
  int lane = tid & 63, w = tid >> 6;
  int quad = lane >> 4, mm = lane & 15;
  int colw = co0 + w * 16;

  bf16x8 Bh[8], Bl[8];
  {
    const short* bh = Woh + (size_t)(colw + mm) * CC + quad * 8;
    const short* bl = Wol + (size_t)(colw + mm) * CC + quad * 8;
#pragma unroll
    for (int kc = 0; kc < 8; ++kc) {
      Bh[kc] = *(const bf16x8*)(bh + kc * 32);
      Bl[kc] = *(const bf16x8*)(bl + kc * 32);
    }
  }
  float bv = bo[colw + mm];

  bf16x8 A0[8], A1[8];
  auto loadA = [&](bf16x8* dst, int g) {
    const short* a = AOh + (size_t)(t0 + g * 16 + mm) * CC + quad * 8;
#pragma unroll
    for (int kc = 0; kc < 8; ++kc) dst[kc] = *(const bf16x8*)(a + kc * 32);
  };
  auto compute = [&](const bf16x8* A, int g) {
    f32x4 aH = {0.f, 0.f, 0.f, 0.f}, aL = {0.f, 0.f, 0.f, 0.f};
#pragma unroll
    for (int kc = 0; kc < 8; ++kc) {
      aH = __builtin_amdgcn_mfma_f32_16x16x32_bf16(A[kc], Bh[kc], aH, 0, 0, 0);
      aL = __builtin_amdgcn_mfma_f32_16x16x32_bf16(A[kc], Bl[kc], aL, 0, 0, 0);
    }
#pragma unroll
    for (int r = 0; r < 4; ++r) {
      int token = t0 + g * 16 + quad * 4 + r;
      out[(size_t)token * CC + colw + mm] = aH[r] + aL[r] + bv;
    }
  };

  loadA(A0, 0);
#pragma unroll
  for (int g = 0; g < 4; g += 2) {
    loadA(A1, g + 1);
    compute(A0, g);
    if (g + 2 < 4) loadA(A0, g + 2);
    compute(A1, g + 1);
  }
}

extern "C" void kernel_launch(void* const* d_in, const int* in_sizes, int n_in,
                              void* d_out, int out_size, void* d_ws, size_t ws_size,
                              hipStream_t stream) {
  (void)in_sizes; (void)n_in; (void)out_size; (void)ws_size;
  const float* x  = (const float*)d_in[0];
  const float* y  = (const float*)d_in[1];
  const float* wq = (const float*)d_in[4];
  const float* gq = (const float*)d_in[5];
  const float* bq = (const float*)d_in[6];
  const float* wk = (const float*)d_in[7];
  const float* gk = (const float*)d_in[8];
  const float* bk = (const float*)d_in[9];
  const float* wv = (const float*)d_in[10];
  const float* gv = (const float*)d_in[11];
  const float* bv = (const float*)d_in[12];
  const float* Wq = (const float*)d_in[13];
  const float* Wk = (const float*)d_in[14];
  const float* Wv = (const float*)d_in[15];
  const float* Wo = (const float*)d_in[16];
  const float* bo = (const float*)d_in[17];
  float* out = (float*)d_out;

  const size_t NP = (size_t)8192 * 256;  // one bf16 plane = 2M shorts
  short* xh  = (short*)d_ws;
  short* yh  = xh + NP;
  short* ch  = yh + NP;            // conv-hi [3] planes
  short* Qh  = ch + 3 * NP;        // head-major [64][1024][32]
  short* Kh  = Qh + NP;            // head-major
  short* Vh  = Kh + NP;            // feature-major, t'-interleaved
  short* AOh = Vh + NP;
  short* Wp  = AOh + NP;           // packed conv weights [3][4][8][9][4][512]
  short* Woh = Wp + (size_t)3 * 9 * 65536;
  short* Wol = Woh + 65536;
  float* st  = (float*)(Wol + 65536);  // 3 x (sum256 + sumsq256)
  float* zf  = st + 1536;              // 512 floats of zeros (OOB DMA source)
  short* zpad = (short*)zf;

  k_prep<<<5120, 256, 0, stream>>>(x, y, wq, wk, wv, Wo, xh, yh, Wp, Woh, Wol, st, zf);

  k_conv<<<dim3(4, 8, 24), 256, 0, stream>>>(xh, yh, Wp, zpad, ch, st);

  k_proj<<<dim3(64, 4, 3), 256, 0, stream>>>(ch, Wq, Wk, Wv, gq, gk, gv,
                                             bq, bk, bv, st, Qh, Kh, Vh);

  k_attn<<<dim3(64, 8), 256, 0, stream>>>(Qh, Kh, Vh, AOh);

  k_out<<<dim3(128, 4), 256, 0, stream>>>(AOh, Woh, Wol, bo, out);
}